// Round 1
// baseline (1501.600 us; speedup 1.0000x reference)
//
#include <hip/hip_runtime.h>
#include <hip/hip_bf16.h>
#include <hip/hip_fp16.h>

// Shapes (fixed per reference)
#define DD   2048
#define DH   1024
#define NBF  128          // B*F
#define NHH  8
#define NOO  16
#define R1   16384        // B*F*H*O rows of edge matrix
#define GR   1024         // B*F*H
#define D3   6144         // 3*D

typedef __attribute__((ext_vector_type(8))) _Float16 half8;
typedef __attribute__((ext_vector_type(4))) float floatx4;

union FHU { unsigned short u; _Float16 h; };
__device__ __forceinline__ unsigned short f2h(float f) { FHU x; x.h = (_Float16)f; return x.u; }
__device__ __forceinline__ float h2f(unsigned short u) { FHU x; x.u = u; return (float)x.h; }
__device__ __forceinline__ float sigm(float x) { return 1.f / (1.f + expf(-x)); }

// ---------------------------------------------------------------------------
// Templated GEMM: out[M,N] = A[M,K] @ Bw[N,K]^T (+bias)
// A is fp32 (ABF=false) or f16 bits (ABF=true); staged to LDS as f16.
// EPI 0: outf[row*ldc+col] = (acc+bias[col])*scale
// EPI 1: logits[row] += sum_col( relu(acc+bias[col]) * wl2[col] )   (atomic)
// EPI 2: outh[row*ldc+col] = f16( (acc+bias[col]) * wrow[row] )
// Tiles: BM=BN=128, BK=32; 256 threads = 4 waves, each wave 64x64.
// ---------------------------------------------------------------------------
template<bool ABF, int EPI>
__global__ __launch_bounds__(256) void gemm_k(
    const void* __restrict__ Av, int lda,
    const float* __restrict__ Bw, int K,
    const float* __restrict__ bias,
    float scale,
    float* __restrict__ outf, unsigned short* __restrict__ outh, int ldc,
    const float* __restrict__ wl2, float* __restrict__ logits,
    const float* __restrict__ wrow)
{
    __shared__ unsigned short As[128][40];   // +8 pad: bank-conflict relief, keeps 16B align
    __shared__ unsigned short Bs[128][40];

    const int tid  = threadIdx.x;
    const int lane = tid & 63;
    const int wv   = tid >> 6;
    const int wr   = wv >> 1, wc = wv & 1;
    const int bm   = blockIdx.y, bn = blockIdx.x;

    floatx4 acc[4][4];
#pragma unroll
    for (int m = 0; m < 4; ++m)
#pragma unroll
        for (int n = 0; n < 4; ++n) acc[m][n] = (floatx4)0.0f;

    const int srow = tid >> 2;          // 0..63
    const int skc  = (tid & 3) << 3;    // 0,8,16,24

    for (int kt = 0; kt < K; kt += 32) {
#pragma unroll
        for (int i = 0; i < 2; ++i) {
            const int row = srow + (i << 6);
            // ---- A tile ----
            if (ABF) {
                const uint4 va = *(const uint4*)((const unsigned short*)Av +
                                  (size_t)(bm * 128 + row) * lda + kt + skc);
                *(uint4*)&As[row][skc] = va;
            } else {
                const float* ap = (const float*)Av + (size_t)(bm * 128 + row) * lda + kt + skc;
                const float4 v0 = *(const float4*)ap;
                const float4 v1 = *(const float4*)(ap + 4);
                uint4 pk;
                pk.x = f2h(v0.x) | ((unsigned)f2h(v0.y) << 16);
                pk.y = f2h(v0.z) | ((unsigned)f2h(v0.w) << 16);
                pk.z = f2h(v1.x) | ((unsigned)f2h(v1.y) << 16);
                pk.w = f2h(v1.z) | ((unsigned)f2h(v1.w) << 16);
                *(uint4*)&As[row][skc] = pk;
            }
            // ---- B tile (weights, always fp32 [N,K]) ----
            const float* bp = Bw + (size_t)(bn * 128 + row) * K + kt + skc;
            const float4 w0 = *(const float4*)bp;
            const float4 w1v = *(const float4*)(bp + 4);
            uint4 pb;
            pb.x = f2h(w0.x) | ((unsigned)f2h(w0.y) << 16);
            pb.y = f2h(w0.z) | ((unsigned)f2h(w0.w) << 16);
            pb.z = f2h(w1v.x) | ((unsigned)f2h(w1v.y) << 16);
            pb.w = f2h(w1v.z) | ((unsigned)f2h(w1v.w) << 16);
            *(uint4*)&Bs[row][skc] = pb;
        }
        __syncthreads();

        const int fr = lane & 15;
        const int fk = (lane >> 4) << 3;
        half8 af[4], bf_[4];
#pragma unroll
        for (int m = 0; m < 4; ++m) af[m]  = *(const half8*)&As[wr * 64 + m * 16 + fr][fk];
#pragma unroll
        for (int n = 0; n < 4; ++n) bf_[n] = *(const half8*)&Bs[wc * 64 + n * 16 + fr][fk];
#pragma unroll
        for (int m = 0; m < 4; ++m)
#pragma unroll
            for (int n = 0; n < 4; ++n)
                acc[m][n] = __builtin_amdgcn_mfma_f32_16x16x32_f16(af[m], bf_[n], acc[m][n], 0, 0, 0);
        __syncthreads();
    }

    // -------- epilogue --------
    const int fr = lane & 15;
    const int er = (lane >> 4) << 2;
    if (EPI == 1) {
        float part[4][4];
#pragma unroll
        for (int m = 0; m < 4; ++m)
#pragma unroll
            for (int e = 0; e < 4; ++e) part[m][e] = 0.f;
#pragma unroll
        for (int n = 0; n < 4; ++n) {
            const int gcol = bn * 128 + wc * 64 + n * 16 + fr;
            const float bc = bias[gcol];
            const float wl = wl2[gcol];
#pragma unroll
            for (int m = 0; m < 4; ++m)
#pragma unroll
                for (int e = 0; e < 4; ++e) {
                    float v = acc[m][n][e] + bc;
                    v = fmaxf(v, 0.f);
                    part[m][e] += v * wl;
                }
        }
#pragma unroll
        for (int m = 0; m < 4; ++m)
#pragma unroll
            for (int e = 0; e < 4; ++e) {
                float p = part[m][e];
                p += __shfl_xor(p, 1);
                p += __shfl_xor(p, 2);
                p += __shfl_xor(p, 4);
                p += __shfl_xor(p, 8);
                if ((lane & 15) == 0) {
                    const int grow = bm * 128 + wr * 64 + m * 16 + er + e;
                    atomicAdd(&logits[grow], p);
                }
            }
    } else {
#pragma unroll
        for (int m = 0; m < 4; ++m) {
            const int grow0 = bm * 128 + wr * 64 + m * 16 + er;
#pragma unroll
            for (int n = 0; n < 4; ++n) {
                const int gcol = bn * 128 + wc * 64 + n * 16 + fr;
                const float bc = bias ? bias[gcol] : 0.f;
#pragma unroll
                for (int e = 0; e < 4; ++e) {
                    const int grow = grow0 + e;
                    const float v = acc[m][n][e] + bc;
                    if (EPI == 0) {
                        outf[(size_t)grow * ldc + gcol] = v * scale;
                    } else {
                        outh[(size_t)grow * ldc + gcol] = f2h(v * wrow[grow]);
                    }
                }
            }
        }
    }
}

// -------- softmax over groups of 16 (the O axis) --------
__global__ void softmax16_k(const float* __restrict__ logits, float* __restrict__ w, int ngroups)
{
    const int g = blockIdx.x * blockDim.x + threadIdx.x;
    if (g >= ngroups) return;
    const float* l = logits + g * 16;
    float mx = l[0];
#pragma unroll
    for (int o = 1; o < 16; ++o) mx = fmaxf(mx, l[o]);
    float e[16], s = 0.f;
#pragma unroll
    for (int o = 0; o < 16; ++o) { e[o] = expf(l[o] - mx); s += e[o]; }
    const float inv = 1.f / s;
#pragma unroll
    for (int o = 0; o < 16; ++o) w[g * 16 + o] = e[o] * inv;
}

// -------- UM1 second half: UM1[r,1024+c] = f16(w1[r]*msg_n[bf*16+o, c]) --------
__global__ void um1h2_k(const float* __restrict__ msgn, const float* __restrict__ w1,
                        unsigned short* __restrict__ um1)
{
    const int idx = blockIdx.x * 256 + threadIdx.x;   // R1*256 threads
    const int r = idx >> 8;
    const int c = (idx & 255) << 2;
    const int bf = r >> 7, o = r & 15;
    const float4 mv = *(const float4*)&msgn[((size_t)(bf * 16 + o)) * DH + c];
    const float wvv = w1[r];
    ushort4 s;
    s.x = f2h(mv.x * wvv); s.y = f2h(mv.y * wvv);
    s.z = f2h(mv.z * wvv); s.w = f2h(mv.w * wvv);
    *(ushort4*)&um1[(size_t)r * DD + DH + c] = s;
}

// -------- V2[g,:] = sum_o w2[g*16+o] * UM1[g*16+o,:]  (f16 in, f32 out) --------
__global__ void v2_k(const unsigned short* __restrict__ um1, const float* __restrict__ w2,
                     float* __restrict__ V2)
{
    const int idx = blockIdx.x * 256 + threadIdx.x;   // GR*512 threads
    const int g = idx >> 9;
    const int c = (idx & 511) << 2;
    float4 a = {0.f, 0.f, 0.f, 0.f};
#pragma unroll
    for (int o = 0; o < 16; ++o) {
        const float wvv = w2[g * 16 + o];
        const ushort4 u = *(const ushort4*)&um1[(size_t)(g * 16 + o) * DD + c];
        a.x += wvv * h2f(u.x); a.y += wvv * h2f(u.y);
        a.z += wvv * h2f(u.z); a.w += wvv * h2f(u.w);
    }
    *(float4*)&V2[(size_t)g * DD + c] = a;
}

// -------- M_sum2 second half: (1/16) sum_o w2 * msg_n --------
__global__ void msum2h2_k(const float* __restrict__ msgn, const float* __restrict__ w2,
                          float* __restrict__ msum2)
{
    const int idx = blockIdx.x * 256 + threadIdx.x;   // GR*256 threads
    const int g = idx >> 8;
    const int c = (idx & 255) << 2;
    const int bf = g >> 3;
    float4 a = {0.f, 0.f, 0.f, 0.f};
#pragma unroll
    for (int o = 0; o < 16; ++o) {
        const float wvv = w2[g * 16 + o];
        const float4 mv = *(const float4*)&msgn[((size_t)(bf * 16 + o)) * DH + c];
        a.x += wvv * mv.x; a.y += wvv * mv.y; a.z += wvv * mv.z; a.w += wvv * mv.w;
    }
    float4 r;
    r.x = a.x * 0.0625f; r.y = a.y * 0.0625f; r.z = a.z * 0.0625f; r.w = a.w * 0.0625f;
    *(float4*)&msum2[(size_t)g * DD + DH + c] = r;
}

// -------- GRU combine: out = (1-z)*n + z*h --------
__global__ void gruc_k(const float* __restrict__ gi, const float* __restrict__ gh,
                       const float* __restrict__ h, float* __restrict__ out, int total)
{
    const int idx = blockIdx.x * 256 + threadIdx.x;
    if (idx >= total) return;
    const int r = idx >> 11, d = idx & 2047;
    const float* gir = gi + (size_t)r * D3;
    const float* ghr = gh + (size_t)r * D3;
    const float rg = sigm(gir[d] + ghr[d]);
    const float zg = sigm(gir[2048 + d] + ghr[2048 + d]);
    const float ng = tanhf(gir[4096 + d] + rg * ghr[4096 + d]);
    out[idx] = (1.f - zg) * ng + zg * h[idx];
}

// -------- All_human = mean over H --------
__global__ void allh_k(const float* __restrict__ humans, float* __restrict__ allh)
{
    const int idx = blockIdx.x * 256 + threadIdx.x;   // NBF*DD threads
    const int bf = idx >> 11, d = idx & 2047;
    float s = 0.f;
#pragma unroll
    for (int hh = 0; hh < NHH; ++hh) s += humans[(size_t)(bf * NHH + hh) * DD + d];
    allh[idx] = s * 0.125f;
}

// -------- transpose final_S_node [B,D,F] -> S_f [B*F, D] --------
__global__ void transp_k(const float* __restrict__ fin, float* __restrict__ sf)
{
    const int idx = blockIdx.x * 256 + threadIdx.x;   // NBF*DD threads
    const int m = idx >> 11, k = idx & 2047;
    const int b = m >> 5, f = m & 31;
    sf[idx] = fin[(size_t)b * (DD * 32) + (size_t)k * 32 + f];
}

// ---------------------------------------------------------------------------
extern "C" void kernel_launch(void* const* d_in, const int* in_sizes, int n_in,
                              void* d_out, int out_size, void* d_ws, size_t ws_size,
                              hipStream_t stream)
{
    const float* S_node = (const float*)d_in[0];
    const float* finalS = (const float*)d_in[1];
    const float* Hn     = (const float*)d_in[2];
    const float* On     = (const float*)d_in[3];
    const float* E0     = (const float*)d_in[4];
    const float* Wn     = (const float*)d_in[5];
    const float* bn     = (const float*)d_in[6];
    const float* We     = (const float*)d_in[7];
    const float* be     = (const float*)d_in[8];
    const float* Wl1    = (const float*)d_in[9];
    const float* bl1    = (const float*)d_in[10];
    const float* Wl2    = (const float*)d_in[11];
    // d_in[12] = bl2: softmax is shift-invariant, unused
    const float* gh_wih = (const float*)d_in[13];
    const float* gh_whh = (const float*)d_in[14];
    const float* gh_bih = (const float*)d_in[15];
    const float* gh_bhh = (const float*)d_in[16];
    const float* gs_wih = (const float*)d_in[17];
    const float* gs_whh = (const float*)d_in[18];
    const float* gs_bih = (const float*)d_in[19];
    const float* gs_bhh = (const float*)d_in[20];
    float* out = (float*)d_out;

    char* ws = (char*)d_ws;
    unsigned short* UM1 = (unsigned short*)ws;          // 67,108,864 B  (R1 x D, f16)
    float* msgn  = (float*)(ws + 67108864);             //  8,388,608 B  (2048 x 1024)
    float* V2    = (float*)(ws + 75497472);             //  8,388,608 B  (GR x D)
    float* Msum2 = (float*)(ws + 83886080);             //  8,388,608 B  (GR x D)
    float* humans= (float*)(ws + 92274688);             //  8,388,608 B  (GR x D)
    float* Allh  = (float*)(ws + 100663296);            //  1,048,576 B
    float* s1    = (float*)(ws + 101711872);            //  1,048,576 B
    float* Sf    = (float*)(ws + 102760448);            //  1,048,576 B
    float* lg1   = (float*)(ws + 103809024);            //     65,536 B
    float* w1    = (float*)(ws + 103874560);
    float* lg2   = (float*)(ws + 103940096);
    float* w2    = (float*)(ws + 104005632);
    // gi/gh alias UM1's region — UM1 is dead after v2_k/G4
    float* gib   = (float*)ws;                          // 25,165,824 B (GR x 3D)
    float* ghb   = (float*)(ws + 25165824);             // 25,165,824 B

    hipMemsetAsync(lg1, 0, R1 * sizeof(float), stream);
    hipMemsetAsync(lg2, 0, R1 * sizeof(float), stream);

    const dim3 blk(256);

    // msg_n = O_nodes @ Wn^T + bn                       [2048,1024]
    gemm_k<false, 0><<<dim3(8, 16), blk, 0, stream>>>(On, DD, Wn, DD, bn, 1.f,
        msgn, nullptr, DH, nullptr, nullptr, nullptr);

    // logits1 += relu(E0 @ Wl1^T + bl1) . Wl2           [16384]
    gemm_k<false, 1><<<dim3(8, 128), blk, 0, stream>>>(E0, DD, Wl1, DD, bl1, 1.f,
        nullptr, nullptr, 0, Wl2, lg1, nullptr);
    softmax16_k<<<4, 256, 0, stream>>>(lg1, w1, GR);

    // UM1[:, :1024] = f16( w1 * (E0 @ We^T + be) )
    gemm_k<false, 2><<<dim3(8, 128), blk, 0, stream>>>(E0, DD, We, DD, be, 1.f,
        nullptr, UM1, DD, nullptr, nullptr, w1);
    // UM1[:, 1024:] = f16( w1 * msg_n )
    um1h2_k<<<16384, 256, 0, stream>>>(msgn, w1, UM1);

    // logits2 from UM1 (f16 A-operand)
    gemm_k<true, 1><<<dim3(8, 128), blk, 0, stream>>>(UM1, DD, Wl1, DD, bl1, 1.f,
        nullptr, nullptr, 0, Wl2, lg2, nullptr);
    softmax16_k<<<4, 256, 0, stream>>>(lg2, w2, GR);

    // V2 = sum_o w2 * UM1 rows; M_sum2 = [ (V2@We^T+be)/16 | (1/16) sum_o w2*msg_n ]
    v2_k<<<2048, 256, 0, stream>>>(UM1, w2, V2);
    gemm_k<false, 0><<<dim3(8, 8), blk, 0, stream>>>(V2, DD, We, DD, be, 0.0625f,
        Msum2, nullptr, DD, nullptr, nullptr, nullptr);
    msum2h2_k<<<1024, 256, 0, stream>>>(msgn, w2, Msum2);

    // humans = GRU(M_sum2, H_nodes)   — UM1 dead from here; gi/gh alias it
    gemm_k<false, 0><<<dim3(48, 8), blk, 0, stream>>>(Msum2, DD, gh_wih, DD, gh_bih, 1.f,
        gib, nullptr, D3, nullptr, nullptr, nullptr);
    gemm_k<false, 0><<<dim3(48, 8), blk, 0, stream>>>(Hn, DD, gh_whh, DD, gh_bhh, 1.f,
        ghb, nullptr, D3, nullptr, nullptr, nullptr);
    gruc_k<<<8192, 256, 0, stream>>>(gib, ghb, Hn, humans, GR * DD);

    allh_k<<<1024, 256, 0, stream>>>(humans, Allh);
    transp_k<<<1024, 256, 0, stream>>>(finalS, Sf);

    // s1 = GRU(All_human, S_node_C4)
    gemm_k<false, 0><<<dim3(48, 1), blk, 0, stream>>>(Allh, DD, gs_wih, DD, gs_bih, 1.f,
        gib, nullptr, D3, nullptr, nullptr, nullptr);
    gemm_k<false, 0><<<dim3(48, 1), blk, 0, stream>>>(S_node, DD, gs_whh, DD, gs_bhh, 1.f,
        ghb, nullptr, D3, nullptr, nullptr, nullptr);
    gruc_k<<<1024, 256, 0, stream>>>(gib, ghb, S_node, s1, NBF * DD);

    // out = GRU(s1, S_f)
    gemm_k<false, 0><<<dim3(48, 1), blk, 0, stream>>>(s1, DD, gs_wih, DD, gs_bih, 1.f,
        gib, nullptr, D3, nullptr, nullptr, nullptr);
    gemm_k<false, 0><<<dim3(48, 1), blk, 0, stream>>>(Sf, DD, gs_whh, DD, gs_bhh, 1.f,
        ghb, nullptr, D3, nullptr, nullptr, nullptr);
    gruc_k<<<1024, 256, 0, stream>>>(gib, ghb, Sf, out, NBF * DD);
}